// Round 1
// baseline (126.655 us; speedup 1.0000x reference)
//
#include <hip/hip_runtime.h>
#include <hip/hip_bf16.h>
#include <stdint.h>

#define NROWS 100000
#define INDIM 512
#define HID 128
#define NCLS 10
#define LEAKY_ALPHA 0.2f

typedef __bf16 bf16x8_t __attribute__((ext_vector_type(8)));
typedef __bf16 bf16x4_t __attribute__((ext_vector_type(4)));
typedef float f32x4_t __attribute__((ext_vector_type(4)));
typedef unsigned short ushort4_t __attribute__((ext_vector_type(4)));

union Frag {
    bf16x8_t v8;
    bf16x4_t v4[2];
};

__device__ __forceinline__ unsigned short f2bf(float x) {
    union { __hip_bfloat16 b; unsigned short u; } cv;
    cv.b = __float2bfloat16(x);
    return cv.u;
}

// ---------------- prep: transpose + cast C and W to K-major bf16 ----------------
// cbt[n][k] = bf16(C[k][n]),  n in [0,128), k in [0,512)
// wbt[n][k] = bf16(W[k][n]),  n in [0,128), k in [0,256)
__global__ void k_prep(const float* __restrict__ C, const float* __restrict__ W,
                       unsigned short* __restrict__ cbt, unsigned short* __restrict__ wbt) {
    int id = blockIdx.x * 256 + threadIdx.x;
    if (id < HID * INDIM) {
        int n = id >> 9;
        int k = id & (INDIM - 1);
        cbt[n * INDIM + k] = f2bf(C[k * HID + n]);
    } else {
        int id2 = id - HID * INDIM;
        if (id2 < HID * 2 * HID) {
            int n = id2 >> 8;
            int k = id2 & (2 * HID - 1);
            wbt[n * 2 * HID + k] = f2bf(W[k * HID + n]);
        }
    }
}

// ---------------- GEMM1: h = features @ C  (bf16 MFMA, fused f32->bf16) ----------------
#define G1_BM 128
#define G1_PAD 40   // padded row stride (bf16 elems) for 32-wide K chunk

__global__ __launch_bounds__(256) void k_gemm1(
    const float* __restrict__ A,            // [NROWS][512] f32
    const unsigned short* __restrict__ BT,  // cbt [128][512] bf16 (K-major)
    unsigned short* __restrict__ Hout)      // [NROWS][128] bf16
{
    __shared__ unsigned short As[G1_BM][G1_PAD];
    __shared__ unsigned short Bs[HID][G1_PAD];

    const int tid  = threadIdx.x;
    const int wave = tid >> 6;
    const int lane = tid & 63;
    const int l15  = lane & 15;
    const int kg   = (lane >> 4) << 2;   // k-group base within 16
    const long row0 = (long)blockIdx.x * G1_BM;

    f32x4_t acc[2][8];
#pragma unroll
    for (int i = 0; i < 2; ++i)
#pragma unroll
        for (int f = 0; f < 8; ++f)
#pragma unroll
            for (int r = 0; r < 4; ++r) acc[i][f][r] = 0.f;

    const int sr = tid >> 1;          // staging row 0..127
    const int sh = (tid & 1) << 4;    // 0 or 16 (element offset)

    for (int k0 = 0; k0 < INDIM; k0 += 32) {
        __syncthreads();
        // stage A tile: 128 rows x 32 k, f32 -> bf16
        {
            long gr = row0 + sr;
            if (gr < NROWS) {
                const float4* s4 = reinterpret_cast<const float4*>(A + gr * INDIM + k0 + sh);
#pragma unroll
                for (int i = 0; i < 4; ++i) {
                    float4 v = s4[i];
                    ushort4_t q;
                    q[0] = f2bf(v.x); q[1] = f2bf(v.y); q[2] = f2bf(v.z); q[3] = f2bf(v.w);
                    *reinterpret_cast<ushort4_t*>(&As[sr][sh + 4 * i]) = q;
                }
            } else {
                ushort4_t q = {0, 0, 0, 0};
#pragma unroll
                for (int i = 0; i < 4; ++i)
                    *reinterpret_cast<ushort4_t*>(&As[sr][sh + 4 * i]) = q;
            }
        }
        // stage B tile: 128 cols x 32 k (already K-major bf16)
        {
            const uint4* s = reinterpret_cast<const uint4*>(BT + sr * INDIM + k0 + sh);
            uint4* d = reinterpret_cast<uint4*>(&Bs[sr][sh]);
            d[0] = s[0]; d[1] = s[1];
        }
        __syncthreads();

        Frag af[2];
#pragma unroll
        for (int i = 0; i < 2; ++i) {
            const unsigned short* p = &As[wave * 32 + i * 16 + l15][kg];
            af[i].v4[0] = *reinterpret_cast<const bf16x4_t*>(p);
            af[i].v4[1] = *reinterpret_cast<const bf16x4_t*>(p + 16);
        }
#pragma unroll
        for (int f = 0; f < 8; ++f) {
            const unsigned short* p = &Bs[f * 16 + l15][kg];
            Frag bfr;
            bfr.v4[0] = *reinterpret_cast<const bf16x4_t*>(p);
            bfr.v4[1] = *reinterpret_cast<const bf16x4_t*>(p + 16);
            acc[0][f] = __builtin_amdgcn_mfma_f32_16x16x32_bf16(af[0].v8, bfr.v8, acc[0][f], 0, 0, 0);
            acc[1][f] = __builtin_amdgcn_mfma_f32_16x16x32_bf16(af[1].v8, bfr.v8, acc[1][f], 0, 0, 0);
        }
    }

    // epilogue: C/D layout col = lane&15, row = (lane>>4)*4 + reg  [m89-verified]
    const int rq = (lane >> 4) << 2;
#pragma unroll
    for (int i = 0; i < 2; ++i)
#pragma unroll
        for (int f = 0; f < 8; ++f)
#pragma unroll
            for (int r = 0; r < 4; ++r) {
                long grow = row0 + wave * 32 + i * 16 + rq + r;
                if (grow < NROWS) Hout[grow * HID + f * 16 + l15] = f2bf(acc[i][f][r]);
            }
}

// ---------------- GEMM2: outs = [h[n1]|h[n2]] @ W, fused @V + leaky + log_softmax ----------------
#define G2_BM 64
#define G2_PA 264   // Ag row stride (bf16), 64*264*2 = 33792 B == 64*132*4 (outs overlay)

__global__ __launch_bounds__(256) void k_gemm2(
    const unsigned short* __restrict__ H,    // [NROWS][128] bf16
    const unsigned short* __restrict__ WBT,  // wbt [128][256] bf16 (K-major)
    const float* __restrict__ V,             // [128][10] f32
    const int* __restrict__ n1, const int* __restrict__ n2,
    float* __restrict__ Out)                 // [NROWS][10] f32
{
    __shared__ unsigned short Ag[G2_BM][G2_PA];
    __shared__ unsigned short Bs[HID][40];
    __shared__ float Vs[HID][12];

    const int tid  = threadIdx.x;
    const int wave = tid >> 6;
    const int lane = tid & 63;
    const int l15  = lane & 15;
    const int kg   = (lane >> 4) << 2;
    const long row0 = (long)blockIdx.x * G2_BM;

    // stage V (pad cols to 12 for 16B-aligned rows)
    for (int i = tid; i < HID * 12; i += 256) {
        int j = i / 12, c = i - j * 12;
        Vs[j][c] = (c < 10) ? V[j * NCLS + c] : 0.f;
    }
    // stage gathered A rows: Ag[i] = [ h[n1[row0+i]] | h[n2[row0+i]] ]
    {
        int i    = tid >> 2;
        int half = (tid >> 1) & 1;
        int sub  = tid & 1;
        long gr  = row0 + i;
        uint4* dst = reinterpret_cast<uint4*>(&Ag[i][half * HID + sub * 64]);
        if (gr < NROWS) {
            int idx = half ? n2[gr] : n1[gr];
            const uint4* src = reinterpret_cast<const uint4*>(H + (long)idx * HID + sub * 64);
#pragma unroll
            for (int t = 0; t < 8; ++t) dst[t] = src[t];
        } else {
            uint4 z = make_uint4(0, 0, 0, 0);
#pragma unroll
            for (int t = 0; t < 8; ++t) dst[t] = z;
        }
    }

    f32x4_t acc[8];
#pragma unroll
    for (int f = 0; f < 8; ++f)
#pragma unroll
        for (int r = 0; r < 4; ++r) acc[f][r] = 0.f;

    __syncthreads();

    const int sn = tid >> 1;
    const int sh = (tid & 1) << 4;
    for (int s = 0; s < 8; ++s) {
        if (s) __syncthreads();
        {
            const uint4* src = reinterpret_cast<const uint4*>(WBT + sn * (2 * HID) + s * 32 + sh);
            uint4* d = reinterpret_cast<uint4*>(&Bs[sn][sh]);
            d[0] = src[0]; d[1] = src[1];
        }
        __syncthreads();

        Frag a;
        const unsigned short* ap = &Ag[wave * 16 + l15][s * 32 + kg];
        a.v4[0] = *reinterpret_cast<const bf16x4_t*>(ap);
        a.v4[1] = *reinterpret_cast<const bf16x4_t*>(ap + 16);
#pragma unroll
        for (int f = 0; f < 8; ++f) {
            const unsigned short* bp = &Bs[f * 16 + l15][kg];
            Frag b;
            b.v4[0] = *reinterpret_cast<const bf16x4_t*>(bp);
            b.v4[1] = *reinterpret_cast<const bf16x4_t*>(bp + 16);
            acc[f] = __builtin_amdgcn_mfma_f32_16x16x32_bf16(a.v8, b.v8, acc[f], 0, 0, 0);
        }
    }

    __syncthreads();   // Ag reads done -> overlay outs on same LDS
    float* outs = reinterpret_cast<float*>(&Ag[0][0]);   // [64][132] f32
    {
        const int rb = wave * 16 + ((lane >> 4) << 2);
#pragma unroll
        for (int f = 0; f < 8; ++f)
#pragma unroll
            for (int r = 0; r < 4; ++r)
                outs[(rb + r) * 132 + f * 16 + l15] = acc[f][r];
    }
    __syncthreads();

    // epilogue: results = leaky(outs @ V); log_softmax per row
    {
        const int i = tid >> 2, q = tid & 3;
        float p[12];
#pragma unroll
        for (int c = 0; c < 12; ++c) p[c] = 0.f;
        const float* orow = &outs[i * 132 + q * 32];
#pragma unroll
        for (int jj = 0; jj < 32; jj += 4) {
            float4 o = *reinterpret_cast<const float4*>(orow + jj);
            float oarr[4] = {o.x, o.y, o.z, o.w};
#pragma unroll
            for (int u = 0; u < 4; ++u) {
                int j = q * 32 + jj + u;
                float ov = oarr[u];
                const float4* vr = reinterpret_cast<const float4*>(&Vs[j][0]);
                float4 va = vr[0], vb = vr[1], vc = vr[2];
                p[0] += ov * va.x; p[1] += ov * va.y; p[2] += ov * va.z; p[3] += ov * va.w;
                p[4] += ov * vb.x; p[5] += ov * vb.y; p[6] += ov * vb.z; p[7] += ov * vb.w;
                p[8] += ov * vc.x; p[9] += ov * vc.y;
            }
        }
#pragma unroll
        for (int c = 0; c < 10; ++c) {
            p[c] += __shfl_xor(p[c], 1, 64);
            p[c] += __shfl_xor(p[c], 2, 64);
        }
        long gr = row0 + i;
        if (q == 0 && gr < NROWS) {
            float m = -1e30f;
#pragma unroll
            for (int c = 0; c < 10; ++c) {
                float x = p[c];
                x = (x >= 0.f) ? x : LEAKY_ALPHA * x;
                p[c] = x;
                m = fmaxf(m, x);
            }
            float sum = 0.f;
#pragma unroll
            for (int c = 0; c < 10; ++c) sum += __expf(p[c] - m);
            float lse = m + __logf(sum);
#pragma unroll
            for (int c = 0; c < 10; ++c) Out[gr * NCLS + c] = p[c] - lse;
        }
    }
}

extern "C" void kernel_launch(void* const* d_in, const int* in_sizes, int n_in,
                              void* d_out, int out_size, void* d_ws, size_t ws_size,
                              hipStream_t stream) {
    const float* features = (const float*)d_in[0];
    const float* C  = (const float*)d_in[1];
    const float* W  = (const float*)d_in[2];
    const float* V  = (const float*)d_in[3];
    const int*   n1 = (const int*)d_in[4];
    const int*   n2 = (const int*)d_in[5];
    float* out = (float*)d_out;

    // workspace layout
    char* ws = (char*)d_ws;
    unsigned short* h   = (unsigned short*)ws;                              // 100000*128*2 = 25,600,000 B
    unsigned short* cbt = (unsigned short*)(ws + 25600000);                 // 128*512*2 = 131,072 B
    unsigned short* wbt = (unsigned short*)(ws + 25600000 + 131072);        // 128*256*2 = 65,536 B

    hipLaunchKernelGGL(k_prep, dim3(384), dim3(256), 0, stream, C, W, cbt, wbt);
    hipLaunchKernelGGL(k_gemm1, dim3((NROWS + G1_BM - 1) / G1_BM), dim3(256), 0, stream,
                       features, cbt, h);
    hipLaunchKernelGGL(k_gemm2, dim3((NROWS + G2_BM - 1) / G2_BM), dim3(256), 0, stream,
                       h, wbt, V, n1, n2, out);
}

// Round 2
// 74.481 us; speedup vs baseline: 1.7005x; 1.7005x over previous
//
#include <hip/hip_runtime.h>
#include <hip/hip_bf16.h>
#include <stdint.h>

#define NROWS 100000
#define INDIM 512
#define HID 128
#define NCLS 10
#define LEAKY_ALPHA 0.2f

typedef __bf16 bf16x8_t __attribute__((ext_vector_type(8)));
typedef __bf16 bf16x4_t __attribute__((ext_vector_type(4)));
typedef float f32x4_t __attribute__((ext_vector_type(4)));
typedef unsigned short ushort8_t __attribute__((ext_vector_type(8)));

union Frag {
    bf16x8_t v8;
    bf16x4_t v4[2];
    unsigned short u[8];
};

__device__ __forceinline__ unsigned short f2bf(float x) {
    union { __hip_bfloat16 b; unsigned short u; } cv;
    cv.b = __float2bfloat16(x);
    return cv.u;
}

__device__ __forceinline__ void gload_lds16(const float* g, float* l) {
    __builtin_amdgcn_global_load_lds(
        (const __attribute__((address_space(1))) unsigned int*)g,
        (__attribute__((address_space(3))) unsigned int*)l, 16, 0, 0);
}

// ---------------- prep ----------------
// cbt[n][k] = bf16(C[k][n])            n<128, k<512   (K-major for GEMM1 B)
// pb[c][p]  = bf16( sum_j W[i][j] V[j][c] ),  i = k(p) under the h'-permutation:
//   h' stores h[row][c] at position p = l15*8+f with c = f*16+l15, i.e.
//   true index i -> position p(i) = (i>>7)*128 + (i&15)*8 + ((i>>4)&7)
__global__ void k_prep(const float* __restrict__ C, const float* __restrict__ W,
                       const float* __restrict__ V,
                       unsigned short* __restrict__ cbt, unsigned short* __restrict__ pb) {
    int id = blockIdx.x * 256 + threadIdx.x;
    if (id < HID * INDIM) {
        int n = id >> 9;
        int k = id & (INDIM - 1);
        cbt[n * INDIM + k] = f2bf(C[k * HID + n]);
    } else {
        int e = id - HID * INDIM;      // e < 16*256
        int c = e >> 8;                // 0..15
        int i = e & 255;               // 0..255
        float s = 0.f;
        if (c < NCLS) {
            const float* wr = W + i * HID;
#pragma unroll 4
            for (int j = 0; j < HID; ++j) s += wr[j] * V[j * NCLS + c];
        }
        int p = ((i >> 7) << 7) | ((i & 15) << 3) | ((i >> 4) & 7);
        pb[c * 256 + p] = f2bf(s);
    }
}

// ---------------- GEMM1: h' = permuted bf16(features @ C) ----------------
// BM=128, BK=32, 4 waves; A staged f32 via global_load_lds (XOR-swizzled via
// pre-swizzled source), B (cbt) reg-staged bf16. 2-phase double buffer.
__global__ __launch_bounds__(256) void k_gemm1(
    const float* __restrict__ A,            // [NROWS][512] f32
    const unsigned short* __restrict__ BT,  // cbt [128][512] bf16
    unsigned short* __restrict__ Hout)      // h' [NROWS][128] bf16 (permuted)
{
    __shared__ float As[2][4096];                 // [128 rows][32 k], swizzled
    __shared__ unsigned short Bs[2][128][40];     // padded rows (80 B stride)

    const int tid  = threadIdx.x;
    const int w    = tid >> 6;
    const int lane = tid & 63;
    const int l15  = lane & 15;
    const int kg   = (lane >> 4) << 2;
    const long row0 = (long)blockIdx.x * 128;

    // A staging source pointers: lane covers LDS chunk offset o = w*4096+i*1024+l*16
    // row = o>>7 ; source k-byte = (o&127) ^ ((row&7)<<4)  (involution, row-preserving)
    const float* aptr[4];
#pragma unroll
    for (int i = 0; i < 4; ++i) {
        int r = w * 32 + i * 8 + (lane >> 3);
        long gr = row0 + r;
        if (gr >= NROWS) gr = NROWS - 1;
        int koff = (((lane & 7) * 16) ^ ((r & 7) << 4)) >> 2;   // floats
        aptr[i] = A + gr * INDIM + koff;
    }
    // B staging: thread -> (row, 32B half)
    const int brow  = tid >> 1;
    const int bhalf = (tid & 1) << 4;
    const unsigned short* bptr = BT + brow * INDIM + bhalf;

    f32x4_t acc[2][8];
#pragma unroll
    for (int i = 0; i < 2; ++i)
#pragma unroll
        for (int f = 0; f < 8; ++f)
#pragma unroll
            for (int r = 0; r < 4; ++r) acc[i][f][r] = 0.f;

    // prologue: stage tile 0
#pragma unroll
    for (int i = 0; i < 4; ++i)
        gload_lds16(aptr[i], &As[0][w * 1024 + i * 256]);
    {
        uint4 b0 = *(const uint4*)(bptr);
        uint4 b1 = *(const uint4*)(bptr + 8);
        *(uint4*)&Bs[0][brow][bhalf]     = b0;
        *(uint4*)&Bs[0][brow][bhalf + 8] = b1;
    }
    __syncthreads();

    for (int t = 0; t < 16; ++t) {
        const int cur = t & 1;
        uint4 bn0, bn1;
        if (t < 15) {
            const int k0n = (t + 1) * 32;
#pragma unroll
            for (int i = 0; i < 4; ++i)
                gload_lds16(aptr[i] + k0n, &As[cur ^ 1][w * 1024 + i * 256]);
            bn0 = *(const uint4*)(bptr + k0n);
            bn1 = *(const uint4*)(bptr + k0n + 8);
        }

        // build A fragments (f32 -> bf16 at read)
        Frag fa[2];
#pragma unroll
        for (int ii = 0; ii < 2; ++ii) {
            const int arow = w * 32 + ii * 16 + l15;
            const int sw = (arow & 7) << 4;
            const float* base = &As[cur][arow * 32];
            f32x4_t alo = *(const f32x4_t*)(base + ((((kg << 2))      ^ sw) >> 2));
            f32x4_t ahi = *(const f32x4_t*)(base + (((64 + (kg << 2)) ^ sw) >> 2));
#pragma unroll
            for (int e = 0; e < 4; ++e) {
                fa[ii].u[e]     = f2bf(alo[e]);
                fa[ii].u[4 + e] = f2bf(ahi[e]);
            }
        }
#pragma unroll
        for (int f = 0; f < 8; ++f) {
            const unsigned short* bp = &Bs[cur][f * 16 + l15][kg];
            Frag fb;
            fb.v4[0] = *(const bf16x4_t*)bp;
            fb.v4[1] = *(const bf16x4_t*)(bp + 16);
            acc[0][f] = __builtin_amdgcn_mfma_f32_16x16x32_bf16(fa[0].v8, fb.v8, acc[0][f], 0, 0, 0);
            acc[1][f] = __builtin_amdgcn_mfma_f32_16x16x32_bf16(fa[1].v8, fb.v8, acc[1][f], 0, 0, 0);
        }

        if (t < 15) {
            *(uint4*)&Bs[cur ^ 1][brow][bhalf]     = bn0;
            *(uint4*)&Bs[cur ^ 1][brow][bhalf + 8] = bn1;
        }
        __syncthreads();
    }

    // epilogue: h'[row][l15*8 + f] = acc col (f*16+l15)  -> 16B store per (ii,r)
    const int rq = (lane >> 4) << 2;
#pragma unroll
    for (int ii = 0; ii < 2; ++ii)
#pragma unroll
        for (int r = 0; r < 4; ++r) {
            long grow = row0 + w * 32 + ii * 16 + rq + r;
            if (grow < NROWS) {
                ushort8_t pk;
#pragma unroll
                for (int f = 0; f < 8; ++f) pk[f] = f2bf(acc[ii][f][r]);
                *(ushort8_t*)(Hout + grow * HID + l15 * 8) = pk;
            }
        }
}

// ---------------- GEMM2: logits = leaky(h'[n1]@P1' + h'[n2]@P2'), log_softmax ----------------
// BM=64 (4 waves x 16 rows), K=256 = [h'(n1) | h'(n2)], N=16 (10 valid classes).
// One MFMA fragment per wave per k-step; single barrier.
__global__ __launch_bounds__(256) void k_gemm2(
    const unsigned short* __restrict__ H,    // h' [NROWS][128] bf16
    const unsigned short* __restrict__ Pb,   // [16][256] bf16, permutation-matched
    const int* __restrict__ n1, const int* __restrict__ n2,
    float* __restrict__ Out)                 // [NROWS][10] f32
{
    __shared__ unsigned short Ag[64][264];   // gathered [h1|h2], 528 B row stride
    __shared__ unsigned short Bsh[16][264];

    const int tid  = threadIdx.x;
    const int w    = tid >> 6;
    const int lane = tid & 63;
    const int l15  = lane & 15;
    const int kg   = (lane >> 4) << 2;
    const long row0 = (long)blockIdx.x * 64;

    // stage Pb (8 KB)
    {
        int c = tid >> 4, seg = tid & 15;
        const uint4* s = (const uint4*)(Pb + c * 256 + seg * 16);
        uint4* d = (uint4*)&Bsh[c][seg * 16];
        d[0] = s[0];
        d[1] = s[1];
    }
    // stage gathered rows: 128 B per thread
    {
        int i = tid >> 2, q = tid & 3, half = q >> 1, sub = q & 1;
        long gr = row0 + i;
        if (gr >= NROWS) gr = NROWS - 1;
        int idx = half ? n2[gr] : n1[gr];
        const uint4* s = (const uint4*)(H + (long)idx * HID + sub * 64);
        uint4* d = (uint4*)&Ag[i][half * HID + sub * 64];
#pragma unroll
        for (int t = 0; t < 8; ++t) d[t] = s[t];
    }
    __syncthreads();

    f32x4_t acc = {0.f, 0.f, 0.f, 0.f};
    const unsigned short* arow = &Ag[w * 16 + l15][0];
    const unsigned short* brw  = &Bsh[l15][0];
#pragma unroll
    for (int s = 0; s < 8; ++s) {
        Frag a, b;
        a.v4[0] = *(const bf16x4_t*)(arow + s * 32 + kg);
        a.v4[1] = *(const bf16x4_t*)(arow + s * 32 + 16 + kg);
        b.v4[0] = *(const bf16x4_t*)(brw + s * 32 + kg);
        b.v4[1] = *(const bf16x4_t*)(brw + s * 32 + 16 + kg);
        acc = __builtin_amdgcn_mfma_f32_16x16x32_bf16(a.v8, b.v8, acc, 0, 0, 0);
    }

    // epilogue: lane col=l15 (class), rows rq+r; softmax across lanes 0..9 of each 16-group
    const int rq = (lane >> 4) << 2;
#pragma unroll
    for (int r = 0; r < 4; ++r) {
        float x = acc[r];
        x = (x >= 0.f) ? x : LEAKY_ALPHA * x;
        float xm = (l15 < NCLS) ? x : -1e30f;
        float m = xm;
        m = fmaxf(m, __shfl_xor(m, 1));
        m = fmaxf(m, __shfl_xor(m, 2));
        m = fmaxf(m, __shfl_xor(m, 4));
        m = fmaxf(m, __shfl_xor(m, 8));
        float e = (l15 < NCLS) ? __expf(x - m) : 0.f;
        float ssum = e;
        ssum += __shfl_xor(ssum, 1);
        ssum += __shfl_xor(ssum, 2);
        ssum += __shfl_xor(ssum, 4);
        ssum += __shfl_xor(ssum, 8);
        float lse = m + __logf(ssum);
        long grow = row0 + w * 16 + rq + r;
        if (l15 < NCLS && grow < NROWS) Out[grow * NCLS + l15] = x - lse;
    }
}

extern "C" void kernel_launch(void* const* d_in, const int* in_sizes, int n_in,
                              void* d_out, int out_size, void* d_ws, size_t ws_size,
                              hipStream_t stream) {
    const float* features = (const float*)d_in[0];
    const float* C  = (const float*)d_in[1];
    const float* W  = (const float*)d_in[2];
    const float* V  = (const float*)d_in[3];
    const int*   n1 = (const int*)d_in[4];
    const int*   n2 = (const int*)d_in[5];
    float* out = (float*)d_out;

    char* ws = (char*)d_ws;
    unsigned short* h   = (unsigned short*)ws;                        // 25,600,000 B
    unsigned short* cbt = (unsigned short*)(ws + 25600000);           // 131,072 B
    unsigned short* pb  = (unsigned short*)(ws + 25600000 + 131072);  // 8,192 B

    hipLaunchKernelGGL(k_prep, dim3(272), dim3(256), 0, stream, C, W, V, cbt, pb);
    hipLaunchKernelGGL(k_gemm1, dim3((NROWS + 127) / 128), dim3(256), 0, stream,
                       features, cbt, h);
    hipLaunchKernelGGL(k_gemm2, dim3((NROWS + 63) / 64), dim3(256), 0, stream,
                       h, pb, n1, n2, out);
}

// Round 3
// 70.867 us; speedup vs baseline: 1.7872x; 1.0510x over previous
//
#include <hip/hip_runtime.h>
#include <hip/hip_bf16.h>
#include <stdint.h>

#define NROWS 100000
#define INDIM 512
#define HID 128
#define NCLS 10
#define LEAKY_ALPHA 0.2f

typedef __bf16 bf16x8_t __attribute__((ext_vector_type(8)));
typedef __bf16 bf16x4_t __attribute__((ext_vector_type(4)));
typedef float f32x4_t __attribute__((ext_vector_type(4)));
typedef unsigned short ushort8_t __attribute__((ext_vector_type(8)));

union Frag {
    bf16x8_t v8;
    bf16x4_t v4[2];
    unsigned short u[8];
};

__device__ __forceinline__ unsigned short f2bf(float x) {
    union { __hip_bfloat16 b; unsigned short u; } cv;
    cv.b = __float2bfloat16(x);
    return cv.u;
}

// Byte address of element (row r, k-base kbase) inside an 8 KB [128 x 32] bf16
// tile image: rows paired into 128-B lines, 16-B units XOR-swizzled by (pair&7).
// Bank-checked: b64 frag reads and b128 writes both land at the conflict minimum.
__device__ __forceinline__ int img_addr(int r, int kbase) {
    int p = r >> 1;
    int o = ((r & 1) << 6) | (kbase << 1);
    return (p << 7) | ((((o >> 4) ^ (p & 7)) << 4) | (o & 15));
}

__device__ __forceinline__ void gload_lds16(const unsigned short* g, unsigned short* l) {
    __builtin_amdgcn_global_load_lds(
        (const __attribute__((address_space(1))) unsigned int*)g,
        (__attribute__((address_space(3))) unsigned int*)l, 16, 0, 0);
}

// ---------------- prep ----------------
// blocks 0..15 : cbt_img[t] = pre-swizzled 8KB tile images of bf16(C^T), k-tile t
// blocks 16..19: pb[c][p(i)] = bf16( sum_j W[i][j] V[j][c] ), h'-permutation folded in
__global__ __launch_bounds__(256) void k_prep(
    const float* __restrict__ C, const float* __restrict__ W, const float* __restrict__ V,
    unsigned short* __restrict__ cbt_img, unsigned short* __restrict__ pb) {
    __shared__ float smem[9536];
    const int b = blockIdx.x, tid = threadIdx.x;
    if (b < 16) {
        // stage C[k0..k0+32][0..128] coalesced -> LDS [32][132]
        float* Cl = smem;
        const int k0 = b << 5;
        const int kr = tid >> 3, ns = (tid & 7) << 4;
        const float4* src = reinterpret_cast<const float4*>(C + (k0 + kr) * HID + ns);
#pragma unroll
        for (int j = 0; j < 4; ++j)
            *reinterpret_cast<float4*>(&Cl[kr * 132 + ns + 4 * j]) = src[j];
        __syncthreads();
        // transpose-read column n, convert, write swizzled image units
        const int n = tid >> 1, kseg = (tid & 1) << 4;
        ushort8_t lo, hi;
#pragma unroll
        for (int j = 0; j < 8; ++j) {
            lo[j] = f2bf(Cl[(kseg + j) * 132 + n]);
            hi[j] = f2bf(Cl[(kseg + 8 + j) * 132 + n]);
        }
        char* dst = (char*)(cbt_img + b * 4096);
        *reinterpret_cast<ushort8_t*>(dst + img_addr(n, kseg))     = lo;
        *reinterpret_cast<ushort8_t*>(dst + img_addr(n, kseg + 8)) = hi;
    } else {
        // pb: block handles i in [i0, i0+64)
        float* Wl = smem;            // [64][129]
        float* Vl = smem + 64 * 129; // [128*10]
        const int i0 = (b - 16) << 6;
        const int ir = tid >> 2, seg = (tid & 3) << 5;
        const float4* ws_ = reinterpret_cast<const float4*>(W + (i0 + ir) * HID + seg);
#pragma unroll
        for (int j = 0; j < 8; ++j)
            *reinterpret_cast<float4*>(&Wl[ir * 129 + seg + 4 * j]) = ws_[j];
        for (int idx = tid; idx < HID * NCLS; idx += 256) Vl[idx] = V[idx];
        __syncthreads();
        for (int o = tid; o < 64 * NCLS; o += 256) {
            int il = o / NCLS, c = o - il * NCLS;
            float s = 0.f;
#pragma unroll 4
            for (int j = 0; j < HID; ++j) s += Wl[il * 129 + j] * Vl[j * NCLS + c];
            int i = i0 + il;
            int p = ((i >> 7) << 7) | ((i & 15) << 3) | ((i >> 4) & 7);
            pb[c * 256 + p] = f2bf(s);
        }
    }
}

// ---------------- GEMM1: h' = permuted bf16(features @ C) ----------------
// BM=128, BK=32, 4 waves. A reg-staged (f32 load -> bf16 convert -> swizzled
// ds_write, T14 issue-early/write-late); B copied linearly via global_load_lds
// from pre-swizzled cbt_img. 32 KB LDS -> 4 blocks/CU.
__global__ __launch_bounds__(256, 4) void k_gemm1(
    const float* __restrict__ A,            // [NROWS][512] f32
    const unsigned short* __restrict__ Bimg, // 16 x 8KB swizzled tile images
    unsigned short* __restrict__ Hout)      // h' [NROWS][128] bf16 (permuted)
{
    __shared__ unsigned short As[2][4096];
    __shared__ unsigned short Bs[2][4096];

    const int tid  = threadIdx.x;
    const int w    = tid >> 6;
    const int lane = tid & 63;
    const int l15  = lane & 15;
    const int kg   = (lane >> 4) << 2;
    const long row0 = (long)blockIdx.x * 128;

    // A staging: thread -> (row, 16-elem half); 64 B f32 load per tile
    const int ar_s = tid >> 1;
    const int kh   = (tid & 1) << 4;
    long gr = row0 + ar_s;
    if (gr >= NROWS) gr = NROWS - 1;
    const float* asrc = A + gr * INDIM + kh;
    const int aw0 = img_addr(ar_s, kh);
    const int aw1 = img_addr(ar_s, kh + 8);

    // B copy source (per-lane) and LDS dest (wave-uniform)
    const unsigned short* bsrc = Bimg + w * 1024 + lane * 8;

    // fragment read byte-addresses (within one 8 KB buffer)
    int ard0[2], ard1[2], brd0[8], brd1[8];
#pragma unroll
    for (int ii = 0; ii < 2; ++ii) {
        int r = w * 32 + ii * 16 + l15;
        ard0[ii] = img_addr(r, kg);
        ard1[ii] = img_addr(r, kg + 16);
    }
#pragma unroll
    for (int f = 0; f < 8; ++f) {
        int cfull = f * 16 + l15;
        brd0[f] = img_addr(cfull, kg);
        brd1[f] = img_addr(cfull, kg + 16);
    }

    f32x4_t acc[2][8];
#pragma unroll
    for (int i = 0; i < 2; ++i)
#pragma unroll
        for (int f = 0; f < 8; ++f)
#pragma unroll
            for (int r = 0; r < 4; ++r) acc[i][f][r] = 0.f;

    const char* asb = (const char*)&As[0][0];
    const char* bsb = (const char*)&Bs[0][0];

    // prologue: stage tile 0
    {
        float4 al[4];
#pragma unroll
        for (int j = 0; j < 4; ++j) al[j] = *reinterpret_cast<const float4*>(asrc + 4 * j);
        gload_lds16(bsrc,       &Bs[0][w * 1024]);
        gload_lds16(bsrc + 512, &Bs[0][w * 1024 + 512]);
        ushort8_t lo, hi;
#pragma unroll
        for (int e = 0; e < 4; ++e) {
            lo[e] = f2bf(al[0][e]); lo[4 + e] = f2bf(al[1][e]);
            hi[e] = f2bf(al[2][e]); hi[4 + e] = f2bf(al[3][e]);
        }
        *(ushort8_t*)((char*)asb + aw0) = lo;
        *(ushort8_t*)((char*)asb + aw1) = hi;
    }
    __syncthreads();

#pragma unroll
    for (int t = 0; t < 16; ++t) {
        const int cur = t & 1;
        float4 al[4];
        if (t < 15) {
            // T14: issue next A loads + B global_load_lds early
#pragma unroll
            for (int j = 0; j < 4; ++j)
                al[j] = *reinterpret_cast<const float4*>(asrc + (t + 1) * 32 + 4 * j);
            const unsigned short* bs = bsrc + (t + 1) * 4096;
            gload_lds16(bs,       &Bs[cur ^ 1][w * 1024]);
            gload_lds16(bs + 512, &Bs[cur ^ 1][w * 1024 + 512]);
        }

        // fragments + MFMA from buf[cur]
        Frag fa[2];
#pragma unroll
        for (int ii = 0; ii < 2; ++ii) {
            fa[ii].v4[0] = *(const bf16x4_t*)(asb + cur * 8192 + ard0[ii]);
            fa[ii].v4[1] = *(const bf16x4_t*)(asb + cur * 8192 + ard1[ii]);
        }
#pragma unroll
        for (int f = 0; f < 8; ++f) {
            Frag fb;
            fb.v4[0] = *(const bf16x4_t*)(bsb + cur * 8192 + brd0[f]);
            fb.v4[1] = *(const bf16x4_t*)(bsb + cur * 8192 + brd1[f]);
            acc[0][f] = __builtin_amdgcn_mfma_f32_16x16x32_bf16(fa[0].v8, fb.v8, acc[0][f], 0, 0, 0);
            acc[1][f] = __builtin_amdgcn_mfma_f32_16x16x32_bf16(fa[1].v8, fb.v8, acc[1][f], 0, 0, 0);
        }

        if (t < 15) {
            // write-late: convert + swizzled ds_write into the other buffer
            ushort8_t lo, hi;
#pragma unroll
            for (int e = 0; e < 4; ++e) {
                lo[e] = f2bf(al[0][e]); lo[4 + e] = f2bf(al[1][e]);
                hi[e] = f2bf(al[2][e]); hi[4 + e] = f2bf(al[3][e]);
            }
            *(ushort8_t*)((char*)asb + (cur ^ 1) * 8192 + aw0) = lo;
            *(ushort8_t*)((char*)asb + (cur ^ 1) * 8192 + aw1) = hi;
            __syncthreads();
        }
    }

    // epilogue: h'[row][l15*8 + f] = acc col (f*16+l15) -> one 16B store per (ii,r)
    const int rq = (lane >> 4) << 2;
#pragma unroll
    for (int ii = 0; ii < 2; ++ii)
#pragma unroll
        for (int r = 0; r < 4; ++r) {
            long grow = row0 + w * 32 + ii * 16 + rq + r;
            if (grow < NROWS) {
                ushort8_t pk;
#pragma unroll
                for (int f = 0; f < 8; ++f) pk[f] = f2bf(acc[ii][f][r]);
                *(ushort8_t*)(Hout + grow * HID + l15 * 8) = pk;
            }
        }
}

// ---------------- GEMM2: logits = leaky(h'[n1]@P1' + h'[n2]@P2'), log_softmax ----------------
__global__ __launch_bounds__(256) void k_gemm2(
    const unsigned short* __restrict__ H,    // h' [NROWS][128] bf16
    const unsigned short* __restrict__ Pb,   // [16][256] bf16, permutation-matched
    const int* __restrict__ n1, const int* __restrict__ n2,
    float* __restrict__ Out)                 // [NROWS][10] f32
{
    __shared__ unsigned short Ag[64][264];
    __shared__ unsigned short Bsh[16][264];

    const int tid  = threadIdx.x;
    const int w    = tid >> 6;
    const int lane = tid & 63;
    const int l15  = lane & 15;
    const int kg   = (lane >> 4) << 2;
    const long row0 = (long)blockIdx.x * 64;

    {
        int c = tid >> 4, seg = tid & 15;
        const uint4* s = (const uint4*)(Pb + c * 256 + seg * 16);
        uint4* d = (uint4*)&Bsh[c][seg * 16];
        d[0] = s[0];
        d[1] = s[1];
    }
    {
        int i = tid >> 2, q = tid & 3, half = q >> 1, sub = q & 1;
        long gr = row0 + i;
        if (gr >= NROWS) gr = NROWS - 1;
        int idx = half ? n2[gr] : n1[gr];
        const uint4* s = (const uint4*)(H + (long)idx * HID + sub * 64);
        uint4* d = (uint4*)&Ag[i][half * HID + sub * 64];
#pragma unroll
        for (int t = 0; t < 8; ++t) d[t] = s[t];
    }
    __syncthreads();

    f32x4_t acc = {0.f, 0.f, 0.f, 0.f};
    const unsigned short* arow = &Ag[w * 16 + l15][0];
    const unsigned short* brw  = &Bsh[l15][0];
#pragma unroll
    for (int s = 0; s < 8; ++s) {
        Frag a, b;
        a.v4[0] = *(const bf16x4_t*)(arow + s * 32 + kg);
        a.v4[1] = *(const bf16x4_t*)(arow + s * 32 + 16 + kg);
        b.v4[0] = *(const bf16x4_t*)(brw + s * 32 + kg);
        b.v4[1] = *(const bf16x4_t*)(brw + s * 32 + 16 + kg);
        acc = __builtin_amdgcn_mfma_f32_16x16x32_bf16(a.v8, b.v8, acc, 0, 0, 0);
    }

    const int rq = (lane >> 4) << 2;
#pragma unroll
    for (int r = 0; r < 4; ++r) {
        float x = acc[r];
        x = (x >= 0.f) ? x : LEAKY_ALPHA * x;
        float xm = (l15 < NCLS) ? x : -1e30f;
        float m = xm;
        m = fmaxf(m, __shfl_xor(m, 1));
        m = fmaxf(m, __shfl_xor(m, 2));
        m = fmaxf(m, __shfl_xor(m, 4));
        m = fmaxf(m, __shfl_xor(m, 8));
        float e = (l15 < NCLS) ? __expf(x - m) : 0.f;
        float ssum = e;
        ssum += __shfl_xor(ssum, 1);
        ssum += __shfl_xor(ssum, 2);
        ssum += __shfl_xor(ssum, 4);
        ssum += __shfl_xor(ssum, 8);
        float lse = m + __logf(ssum);
        long grow = row0 + w * 16 + rq + r;
        if (l15 < NCLS && grow < NROWS) Out[grow * NCLS + l15] = x - lse;
    }
}

extern "C" void kernel_launch(void* const* d_in, const int* in_sizes, int n_in,
                              void* d_out, int out_size, void* d_ws, size_t ws_size,
                              hipStream_t stream) {
    const float* features = (const float*)d_in[0];
    const float* C  = (const float*)d_in[1];
    const float* W  = (const float*)d_in[2];
    const float* V  = (const float*)d_in[3];
    const int*   n1 = (const int*)d_in[4];
    const int*   n2 = (const int*)d_in[5];
    float* out = (float*)d_out;

    char* ws = (char*)d_ws;
    unsigned short* h    = (unsigned short*)ws;                        // 25,600,000 B
    unsigned short* cbt  = (unsigned short*)(ws + 25600000);           // 131,072 B (16 x 8KB images)
    unsigned short* pb   = (unsigned short*)(ws + 25600000 + 131072);  // 8,192 B

    hipLaunchKernelGGL(k_prep, dim3(20), dim3(256), 0, stream, C, W, V, cbt, pb);
    hipLaunchKernelGGL(k_gemm1, dim3((NROWS + 127) / 128), dim3(256), 0, stream,
                       features, cbt, h);
    hipLaunchKernelGGL(k_gemm2, dim3((NROWS + 63) / 64), dim3(256), 0, stream,
                       h, pb, n1, n2, out);
}